// Round 3
// baseline (638.460 us; speedup 1.0000x reference)
//
#include <hip/hip_runtime.h>
#include <math.h>

#define HH   768
#define WW   768
#define LL   8
#define NPIX (HH*WW)
#define NLVL (NPIX*LL)
#define BLKI 64            /* pixels per block in k_iter1 */
#define THRI 128           /* threads per block in k_iter1: 2 threads/pixel (4-z split) */
#define REC  37            /* padded LDS record stride: gcd(37-32,32)=1 -> conflict-free */

#define SIGMAP (1.0f/11.0f)   /* 1/(3+L) */
#define TAUMU  (1.0f/11.0f)   /* 1/(2+PROJ/4) */
#define TAUU   (1.0f/6.0f)
#define LMBDA  0.1f
#define NUC    0.01f

__device__ __forceinline__ float4 ld4(const float* p){ return *reinterpret_cast<const float4*>(p); }
__device__ __forceinline__ void  st4(float* p, float4 v){ *reinterpret_cast<float4*>(p) = v; }

// cubic-root parabola projection for one (pixel, z) element
__device__ __forceinline__ void parabola1(float u1, float u2, float u3, float quad,
                                          float& p1n, float& p2n, float& p3n)
{
  float nn = u1*u1 + u2*u2;
  float Bv = 0.25f*nn - quad;
  if (u3 < Bv) {
    float y    = u3 + quad;
    float norm = sqrtf(nn);
    float a    = 0.5f*norm;
    float b    = (2.0f/3.0f)*(1.0f - 0.5f*y);
    float sb   = sqrtf(fmaxf(-b, 0.0f));
    float sb3  = sb*sb*sb;
    float d    = (b < 0.0f) ? (a - sb3)*(a + sb3) : (a*a + b*b*b);
    float v;
    if (d < 0.0f) {
      float sb3s = (sb > 0.0f) ? sb3 : 1.0f;
      float ca   = fminf(fmaxf(a/sb3s, -1.0f), 1.0f);
      v = 2.0f*sb*cosf(acosf(ca)*(1.0f/3.0f));
    } else {
      float sd = sqrtf(d);
      float c  = cbrtf(a + sd);
      v = (c == 0.0f) ? 0.0f : (c - b/c);
    }
    float nsafe = (norm == 0.0f) ? 1.0f : norm;
    float scale = (v + v)/nsafe;                // v/0.5/norm
    p1n = (norm == 0.0f) ? 0.0f : scale*u1;
    p2n = (norm == 0.0f) ? 0.0f : scale*u2;
    p3n = 0.25f*(p1n*p1n + p2n*p2n) - quad;
  } else {
    p1n = u1; p2n = u2; p3n = u3;
  }
}

// stage one proj array (BLKI pixels x 36 floats) into LDS records of stride REC.
// Coalesced: lane reads float4 at flat index, scatters to padded record.
// 64*36/4 = 576 float4 over 128 threads: 4 full rounds + half tail (wave-uniform).
// off = g4 % 36 is always <= 32, so a float4 never straddles two records.
__device__ __forceinline__ void stage1_128(const float* __restrict__ g, float* __restrict__ lds, int tid)
{
  #pragma unroll
  for (int j = 0; j < 4; ++j) {
    int g4 = (tid + THRI*j) * 4;         // element index, multiple of 4
    float4 v = ld4(g + g4);
    int pl  = g4 / 36;                   // local pixel (magic-mul)
    int off = g4 - pl*36;
    float* d = lds + pl*REC + off;
    d[0]=v.x; d[1]=v.y; d[2]=v.z; d[3]=v.w;
  }
  if (tid < 64) {                        // wave-uniform tail (wave 0)
    int g4 = (tid + 512) * 4;
    float4 v = ld4(g + g4);
    int pl  = g4 / 36;
    int off = g4 - pl*36;
    float* d = lds + pl*REC + off;
    d[0]=v.x; d[1]=v.y; d[2]=v.z; d[3]=v.w;
  }
}

// l2-projected component: replicates the original scan's per-K arithmetic
// exactly (same expressions, same condition) so results stay bit-identical.
template<int SEL>
__device__ __forceinline__ float celem(float m1, float m2)
{
  float nrm = sqrtf(m1*m1 + m2*m2);
  float o = (SEL == 0) ? m1 : m2;
  if (nrm > NUC) o = o * (NUC/nrm);
  return o;
}

// stage the l2-projected difference component SEL (0: c1 from s1-mb1, 1: c2
// from s2-mb2) into LDS.  Loads all four arrays (nrm couples them); the
// second pass re-reads them L1/L2-hot.
template<int SEL>
__device__ __forceinline__ void stage_c(const float* __restrict__ ga1, const float* __restrict__ gb1,
                                        const float* __restrict__ ga2, const float* __restrict__ gb2,
                                        float* __restrict__ lds, int tid)
{
  #pragma unroll
  for (int j = 0; j < 4; ++j) {
    int g4 = (tid + THRI*j) * 4;
    float4 a1 = ld4(ga1 + g4), b1 = ld4(gb1 + g4);
    float4 a2 = ld4(ga2 + g4), b2 = ld4(gb2 + g4);
    int pl  = g4 / 36;
    int off = g4 - pl*36;
    float* d = lds + pl*REC + off;
    d[0] = celem<SEL>(a1.x-b1.x, a2.x-b2.x);
    d[1] = celem<SEL>(a1.y-b1.y, a2.y-b2.y);
    d[2] = celem<SEL>(a1.z-b1.z, a2.z-b2.z);
    d[3] = celem<SEL>(a1.w-b1.w, a2.w-b2.w);
  }
  if (tid < 64) {
    int g4 = (tid + 512) * 4;
    float4 a1 = ld4(ga1 + g4), b1 = ld4(gb1 + g4);
    float4 a2 = ld4(ga2 + g4), b2 = ld4(gb2 + g4);
    int pl  = g4 / 36;
    int off = g4 - pl*36;
    float* d = lds + pl*REC + off;
    d[0] = celem<SEL>(a1.x-b1.x, a2.x-b2.x);
    d[1] = celem<SEL>(a1.y-b1.y, a2.y-b2.y);
    d[2] = celem<SEL>(a1.z-b1.z, a2.z-b2.z);
    d[3] = celem<SEL>(a1.w-b1.w, a2.w-b2.w);
  }
}

// membership sums for the half z-range [ZB, ZB+4), single array:
// ms[z] accumulates over K in ASCENDING order -> bit-identical to the
// original full-range scan (no reassociation).
template<int ZB>
__device__ __forceinline__ void memb_scan1(const float* __restrict__ r, float (&ms)[4])
{
  int K = 0;
  #pragma unroll
  for (int k1 = 0; k1 < 8; ++k1) {
    #pragma unroll
    for (int k2 = k1; k2 < 8; ++k2) {
      if (k2 >= ZB && k1 < ZB + 4) {     // compile-time after unroll
        float v = r[K];
        #pragma unroll
        for (int z = (k1 > ZB ? k1 : ZB); z <= (k2 < ZB+3 ? k2 : ZB+3); ++z)
          ms[z-ZB] += v;
      }
      ++K;
    }
  }
}

// A-scan for the half z-range [ZB, ZB+4): reads the pre-projected c value
// from LDS, subtracts the p-sum term, accumulates per K ascending.
template<int ZB>
__device__ __forceinline__ void projA_scan(const float* __restrict__ r, const float (&pre)[9],
                                           float (&A)[4])
{
  int K = 0;
  #pragma unroll
  for (int k1 = 0; k1 < 8; ++k1) {
    #pragma unroll
    for (int k2 = k1; k2 < 8; ++k2) {
      if (k2 >= ZB && k1 < ZB + 4) {
        float d = r[K] - (pre[k2+1] - pre[k1]);
        #pragma unroll
        for (int z = (k1 > ZB ? k1 : ZB); z <= (k2 < ZB+3 ? k2 : ZB+3); ++z)
          A[z-ZB] += d;
      }
      ++K;
    }
  }
}

// ---------------- iteration 1: parabola + l2projection + mu-update ----------
// 128 threads / 64 pixels: thread pair (t, t+64) shares pixel t&63 and splits
// the 8 levels 4/4 (hi = tid>>6 is wave-uniform).  Single 9.5 KB LDS buffer,
// sequentially re-staged (mu1, mu2, exchange, c1, c2) -> 16 blocks/CU =
// 32 waves/CU (100% cap).  All global access is float4 (16 B/lane).
__global__ __launch_bounds__(THRI, 8) void k_iter1(
  const float* __restrict__ ubar, const float* __restrict__ p1,
  const float* __restrict__ p2,   const float* __restrict__ p3,
  const float* __restrict__ s1,   const float* __restrict__ s2,
  const float* __restrict__ mu1,  const float* __restrict__ mu2,
  const float* __restrict__ mb1,  const float* __restrict__ mb2,
  const float* __restrict__ f,
  float* __restrict__ op1, float* __restrict__ op2, float* __restrict__ op3,
  float* __restrict__ oms1, float* __restrict__ oms2)
{
  __shared__ float sBuf[BLKI*REC];   // 9472 B -> 16 blocks/CU

  const int tid  = threadIdx.x;
  const int lpx  = tid & 63;                  // local pixel
  const int hi   = tid >> 6;                  // wave-uniform: 0 -> z 0..3, 1 -> z 4..7
  const int zb   = hi * 4;
  const int blk0 = blockIdx.x * BLKI;         // first pixel of this block
  const int p    = blk0 + lpx;                // grid is exact, no bounds check
  const int w  = p % WW;
  const int h  = p / WW;
  const int pr = (w < WW-1) ? p+1  : p;       // clamped -> diff becomes 0
  const int pd = (h < HH-1) ? p+WW : p;

  // ---- phase A: stage mu1, scan ms1; restage mu2, scan ms2 ----
  stage1_128(mu1 + (size_t)blk0*36, sBuf, tid);
  __syncthreads();
  const float* rC = sBuf + lpx*REC;
  float ms1[4] = {0.f,0.f,0.f,0.f};
  if (hi) memb_scan1<4>(rC, ms1); else memb_scan1<0>(rC, ms1);
  __syncthreads();                 // ms1 reads done before overwrite
  stage1_128(mu2 + (size_t)blk0*36, sBuf, tid);
  __syncthreads();
  float ms2[4] = {0.f,0.f,0.f,0.f};
  if (hi) memb_scan1<4>(rC, ms2); else memb_scan1<0>(rC, ms2);

  // ---- phase B: parabola for this thread's 4 levels (pure registers) ------
  float4 ubq  = ld4(ubar + (size_t)p *8 + zb);
  float  ubx  = hi ? 0.f : ubar[(size_t)p*8 + 4];   // lo needs ub[4] for du3 at z=3
  float4 ubrq = ld4(ubar + (size_t)pr*8 + zb);
  float4 ubdq = ld4(ubar + (size_t)pd*8 + zb);
  float4 p1q  = ld4(p1 + (size_t)p*8 + zb);
  float4 p2q  = ld4(p2 + (size_t)p*8 + zb);
  float4 p3q  = ld4(p3 + (size_t)p*8 + zb);
  const float fv = f[p];

  float ubv[5]  = {ubq.x, ubq.y, ubq.z, ubq.w, ubx};
  float ubrv[4] = {ubrq.x, ubrq.y, ubrq.z, ubrq.w};
  float ubdv[4] = {ubdq.x, ubdq.y, ubdq.z, ubdq.w};
  float p1v[4]  = {p1q.x, p1q.y, p1q.z, p1q.w};
  float p2v[4]  = {p2q.x, p2q.y, p2q.z, p2q.w};
  float p3v[4]  = {p3q.x, p3q.y, p3q.z, p3q.w};

  float pn1[4], pn2[4], pn3[4];
  #pragma unroll
  for (int i = 0; i < 4; ++i) {
    int z = zb + i;
    float du1 = ubdv[i] - ubv[i];
    float du2 = ubrv[i] - ubv[i];
    float du3 = (z < 7) ? (ubv[i+1] - ubv[i]) : 0.f;
    float u1 = p1v[i] + SIGMAP*(du1 + ms1[i]);
    float u2 = p2v[i] + SIGMAP*(du2 + ms2[i]);
    float u3 = p3v[i] + SIGMAP*du3;
    float t  = (float)(z+1)*0.125f - fv;
    float quad = LMBDA*t*t;
    parabola1(u1,u2,u3,quad, pn1[i],pn2[i],pn3[i]);
  }
  st4(op1 + (size_t)p*8 + zb, make_float4(pn1[0],pn1[1],pn1[2],pn1[3]));
  st4(op2 + (size_t)p*8 + zb, make_float4(pn2[0],pn2[1],pn2[2],pn2[3]));
  st4(op3 + (size_t)p*8 + zb, make_float4(pn3[0],pn3[1],pn3[2],pn3[3]));

  // ---- exchange pn1/pn2 between the pair for full-range prefix sums ------
  __syncthreads();                 // all mu2 scan reads done; sBuf reusable
  float* ex1 = sBuf;               // [8][BLKI] row-per-z, lane-consecutive px
  float* ex2 = sBuf + 8*BLKI;      // 1024 floats total, fits in sBuf
  #pragma unroll
  for (int i = 0; i < 4; ++i) {
    ex1[(zb+i)*BLKI + lpx] = pn1[i];
    ex2[(zb+i)*BLKI + lpx] = pn2[i];
  }
  __syncthreads();
  float pre1[9], pre2[9];
  pre1[0] = 0.f; pre2[0] = 0.f;
  #pragma unroll
  for (int z = 0; z < 8; ++z) {
    pre1[z+1] = pre1[z] + ex1[z*BLKI + lpx];
    pre2[z+1] = pre2[z] + ex2[z*BLKI + lpx];
  }

  // ---- phase C: stage projected c1, scan A1; restage c2, scan A2 ----
  __syncthreads();                 // prefix reads done before overwrite
  stage_c<0>(s1 + (size_t)blk0*36, mb1 + (size_t)blk0*36,
             s2 + (size_t)blk0*36, mb2 + (size_t)blk0*36, sBuf, tid);
  __syncthreads();
  float A1[4] = {0.f,0.f,0.f,0.f};
  if (hi) projA_scan<4>(rC, pre1, A1); else projA_scan<0>(rC, pre1, A1);
  __syncthreads();                 // A1 reads done before overwrite
  stage_c<1>(s1 + (size_t)blk0*36, mb1 + (size_t)blk0*36,
             s2 + (size_t)blk0*36, mb2 + (size_t)blk0*36, sBuf, tid);
  __syncthreads();
  float A2[4] = {0.f,0.f,0.f,0.f};
  if (hi) projA_scan<4>(rC, pre2, A2); else projA_scan<0>(rC, pre2, A2);

  st4(oms1 + (size_t)p*8 + zb,
      make_float4(ms1[0] + TAUMU*A1[0], ms1[1] + TAUMU*A1[1],
                  ms1[2] + TAUMU*A1[2], ms1[3] + TAUMU*A1[3]));
  st4(oms2 + (size_t)p*8 + zb,
      make_float4(ms2[0] + TAUMU*A2[0], ms2[1] + TAUMU*A2[1],
                  ms2[2] + TAUMU*A2[2], ms2[3] + TAUMU*A2[3]));
}

// ---------------- iteration 2: parabola only, musum read from ws ------------
// 2 threads/pixel (4 levels each): halves per-thread serial chain + regs.
__global__ __launch_bounds__(256, 8) void k_parab2(
  const float* __restrict__ ubar,
  float* __restrict__ p1, float* __restrict__ p2, float* __restrict__ p3,
  const float* __restrict__ ms1g, const float* __restrict__ ms2g,
  const float* __restrict__ f)
{
  const int t  = blockIdx.x*blockDim.x + threadIdx.x;   // grid exact: 2*NPIX
  const int p  = t >> 1;
  const int hi = t & 1;
  const int zb = hi * 4;
  const int w  = p % WW;
  const int h  = p / WW;
  const int pr = (w < WW-1) ? p+1  : p;
  const int pd = (h < HH-1) ? p+WW : p;

  float4 ubq  = ld4(ubar + (size_t)p *8 + zb);
  float  ubx  = hi ? 0.f : ubar[(size_t)p*8 + 4];   // du3 at z=3 needs ub[4]
  float4 ubrq = ld4(ubar + (size_t)pr*8 + zb);
  float4 ubdq = ld4(ubar + (size_t)pd*8 + zb);
  float4 p1q  = ld4(p1 + (size_t)p*8 + zb);
  float4 p2q  = ld4(p2 + (size_t)p*8 + zb);
  float4 p3q  = ld4(p3 + (size_t)p*8 + zb);
  float4 m1q  = ld4(ms1g + (size_t)p*8 + zb);
  float4 m2q  = ld4(ms2g + (size_t)p*8 + zb);
  const float fv = f[p];

  float ubv[5]  = {ubq.x, ubq.y, ubq.z, ubq.w, ubx};
  float ubrv[4] = {ubrq.x, ubrq.y, ubrq.z, ubrq.w};
  float ubdv[4] = {ubdq.x, ubdq.y, ubdq.z, ubdq.w};
  float p1v[4]  = {p1q.x, p1q.y, p1q.z, p1q.w};
  float p2v[4]  = {p2q.x, p2q.y, p2q.z, p2q.w};
  float p3v[4]  = {p3q.x, p3q.y, p3q.z, p3q.w};
  float ms1[4]  = {m1q.x, m1q.y, m1q.z, m1q.w};
  float ms2[4]  = {m2q.x, m2q.y, m2q.z, m2q.w};

  float pn1[4], pn2[4], pn3[4];
  #pragma unroll
  for (int i = 0; i < 4; ++i) {
    int z = zb + i;
    float du1 = ubdv[i] - ubv[i];
    float du2 = ubrv[i] - ubv[i];
    float du3 = (z < 7) ? (ubv[i+1] - ubv[i]) : 0.f;
    float u1 = p1v[i] + SIGMAP*(du1 + ms1[i]);
    float u2 = p2v[i] + SIGMAP*(du2 + ms2[i]);
    float u3 = p3v[i] + SIGMAP*du3;
    float tt = (float)(z+1)*0.125f - fv;
    float quad = LMBDA*tt*tt;
    parabola1(u1,u2,u3,quad, pn1[i],pn2[i],pn3[i]);
  }
  st4(p1 + (size_t)p*8 + zb, make_float4(pn1[0],pn1[1],pn1[2],pn1[3]));
  st4(p2 + (size_t)p*8 + zb, make_float4(pn2[0],pn2[1],pn2[2],pn2[3]));
  st4(p3 + (size_t)p*8 + zb, make_float4(pn3[0],pn3[1],pn3[2],pn3[3]));
}

// ---------------- clipping: 2 threads/pixel (4 levels each) -----------------
__global__ __launch_bounds__(256, 8) void k_clip(
  const float* __restrict__ uin,
  const float* __restrict__ p1, const float* __restrict__ p2,
  const float* __restrict__ p3,
  float* __restrict__ uout, float* __restrict__ ubarout)
{
  const int t  = blockIdx.x*blockDim.x + threadIdx.x;   // grid exact: 2*NPIX
  const int p  = t >> 1;
  const int hi = t & 1;
  const int zb = hi * 4;
  const int w  = p % WW;
  const int h  = p / WW;
  const int pu = (h > 0) ? p-WW : p;
  const int pl = (w > 0) ? p-1  : p;

  float4 uq   = ld4(uin + (size_t)p *8 + zb);
  float4 a1q  = ld4(p1  + (size_t)p *8 + zb);
  float4 a1uq = ld4(p1  + (size_t)pu*8 + zb);
  float4 a2q  = ld4(p2  + (size_t)p *8 + zb);
  float4 a2lq = ld4(p2  + (size_t)pl*8 + zb);
  float4 a3q  = ld4(p3  + (size_t)p *8 + zb);
  float  a3m  = hi ? p3[(size_t)p*8 + 3] : 0.f;   // d3 at z=4 needs p3[3]

  float uv[4]  = {uq.x, uq.y, uq.z, uq.w};
  float a1[4]  = {a1q.x, a1q.y, a1q.z, a1q.w};
  float a1u[4] = {a1uq.x, a1uq.y, a1uq.z, a1uq.w};
  float a2[4]  = {a2q.x, a2q.y, a2q.z, a2q.w};
  float a2l[4] = {a2lq.x, a2lq.y, a2lq.z, a2lq.w};
  float a3[4]  = {a3q.x, a3q.y, a3q.z, a3q.w};

  const float fh1 = (h < HH-1) ? 1.f : 0.f;
  const float fh0 = (h > 0)    ? 1.f : 0.f;
  const float fw1 = (w < WW-1) ? 1.f : 0.f;
  const float fw0 = (w > 0)    ? 1.f : 0.f;

  float un[4], ubn[4];
  #pragma unroll
  for (int i = 0; i < 4; ++i) {
    int z = zb + i;
    float d1 = fh1*a1[i] - fh0*a1u[i];
    float d2 = fw1*a2[i] - fw0*a2l[i];
    float upper = (z < 7) ? a3[i] : 0.f;
    float lower = (z > 0) ? ((i > 0) ? a3[i-1] : a3m) : 0.f;
    float d3 = upper - lower;
    float x  = uv[i] + TAUU*(d1+d2+d3);
    x = fminf(fmaxf(x, 0.f), 1.f);
    un[i]  = x;
    ubn[i] = 2.f*x - uv[i];
  }
  st4(uout + (size_t)p*8 + zb, make_float4(un[0],un[1],un[2],un[3]));
  if (ubarout) st4(ubarout + (size_t)p*8 + zb, make_float4(ubn[0],ubn[1],ubn[2],ubn[3]));
}

extern "C" void kernel_launch(void* const* d_in, const int* in_sizes, int n_in,
                              void* d_out, int out_size, void* d_ws, size_t ws_size,
                              hipStream_t stream)
{
  const float* u    = (const float*)d_in[0];
  const float* ubar = (const float*)d_in[1];
  const float* p1   = (const float*)d_in[2];
  const float* p2   = (const float*)d_in[3];
  const float* p3   = (const float*)d_in[4];
  const float* s1   = (const float*)d_in[5];
  const float* s2   = (const float*)d_in[6];
  const float* mu1  = (const float*)d_in[7];
  const float* mu2  = (const float*)d_in[8];
  const float* mb1  = (const float*)d_in[9];
  const float* mb2  = (const float*)d_in[10];
  const float* f    = (const float*)d_in[11];

  float* ws   = (float*)d_ws;           // 6 level-sized buffers = 113.2 MB
  float* wp1  = ws;
  float* wp2  = ws + 1*(size_t)NLVL;
  float* wp3  = ws + 2*(size_t)NLVL;
  float* wms1 = ws + 3*(size_t)NLVL;
  float* wms2 = ws + 4*(size_t)NLVL;
  float* wub  = ws + 5*(size_t)NLVL;
  float* uo   = (float*)d_out;

  // iter 1: parabola + l2proj + mu (s/mubar of iter1 are dead beyond this)
  k_iter1 <<<dim3(NPIX/BLKI), dim3(THRI), 0, stream>>>(
      ubar,p1,p2,p3,s1,s2,mu1,mu2,mb1,mb2,f, wp1,wp2,wp3,wms1,wms2);
  // iter 1: clipping -> u^1 (d_out), ubar^1 (ws)
  k_clip  <<<dim3(NPIX*2/256), dim3(256), 0, stream>>>(u, wp1,wp2,wp3, uo, wub);
  // iter 2: parabola (l2proj/mu of iter2 are dead w.r.t. output u)
  k_parab2<<<dim3(NPIX*2/256), dim3(256), 0, stream>>>(wub, wp1,wp2,wp3, wms1,wms2, f);
  // iter 2: clipping, u only, in-place on d_out
  k_clip  <<<dim3(NPIX*2/256), dim3(256), 0, stream>>>(uo, wp1,wp2,wp3, uo, nullptr);
}